// Round 2
// baseline (647.245 us; speedup 1.0000x reference)
//
#include <hip/hip_runtime.h>
#include <cmath>
#include <cstdint>

#define BB 16
#define NN_ 1024
#define DD 256

constexpr float INV_T = 1.0f / 0.07f;

typedef __attribute__((ext_vector_type(8))) short bf16x8;
typedef __attribute__((ext_vector_type(4))) float f32x4;

static __device__ __forceinline__ float b2f(ushort u) {
  union { uint i; float f; } c; c.i = ((uint)u) << 16; return c.f;
}
static __device__ __forceinline__ ushort f2b(float f) {
  union { float f; uint i; } c; c.f = f;
  uint r = c.i + 0x7fffu + ((c.i >> 16) & 1u);
  return (ushort)(r >> 16);
}

// ---------------- row normalize: z(f32) -> zn(bf16) ----------------
__global__ __launch_bounds__(256) void k_norm(const float* __restrict__ z, ushort* __restrict__ zn) {
  const int row = blockIdx.x;
  const int t = threadIdx.x;
  const size_t base = (size_t)row * DD + t;
  float v = z[base];
  float ss = v * v;
#pragma unroll
  for (int o = 32; o; o >>= 1) ss += __shfl_xor(ss, o);
  __shared__ float par[4];
  if ((t & 63) == 0) par[t >> 6] = ss;
  __syncthreads();
  float tot = par[0] + par[1] + par[2] + par[3];
  zn[base] = f2b(v / (sqrtf(tot) + 1e-12f));
}

// ---------------- MFMA NT GEMM: C = U * V^T, U:[N][K], V:[N][K] bf16 ----------------
// MODE 0: store bf16 C
// MODE 1: store bf16 C + den[row] += sum_col exp(c*INV_T) skipping row==col
// MODE 2: den only (no skip)
// MODE 3: store C = bf16( acc + add1[pos] + add2[pos] )
template <int MODE>
__global__ __launch_bounds__(256) void k_gemm_nt(const ushort* __restrict__ U, const ushort* __restrict__ V,
                                                 ushort* __restrict__ C, const ushort* __restrict__ add1,
                                                 const ushort* __restrict__ add2, float* __restrict__ den,
                                                 int K) {
  __shared__ __align__(16) short As[128][56];
  __shared__ __align__(16) short Bs[128][56];
  const int t = threadIdx.x;
  const int b = blockIdx.z;
  const int row0 = blockIdx.y << 7, col0 = blockIdx.x << 7;
  const size_t ub = (size_t)b * NN_ * K;
  const size_t cb = (size_t)b * NN_ * NN_;
  const int lane = t & 63, wv = t >> 6;
  const int wr = wv >> 1, wc = wv & 1;
  const int l15 = lane & 15, slot = lane >> 4;
  const int sr = t >> 2;           // 0..63
  const int sk = (t & 3) << 3;     // 0,8,16,24

  f32x4 acc[4][4];
#pragma unroll
  for (int i = 0; i < 4; ++i)
#pragma unroll
    for (int j = 0; j < 4; ++j)
#pragma unroll
      for (int e = 0; e < 4; ++e) acc[i][j][e] = 0.f;

  for (int k0 = 0; k0 < K; k0 += 32) {
    const ushort* up = U + ub + (size_t)(row0 + sr) * K + (k0 + sk);
    const uint4 av0 = *(const uint4*)up;
    const uint4 av1 = *(const uint4*)(up + (size_t)64 * K);
    const ushort* vp = V + ub + (size_t)(col0 + sr) * K + (k0 + sk);
    const uint4 bv0 = *(const uint4*)vp;
    const uint4 bv1 = *(const uint4*)(vp + (size_t)64 * K);
    __syncthreads();  // previous iteration's fragment reads complete
    *(uint4*)&As[sr][sk] = av0;
    *(uint4*)&As[sr + 64][sk] = av1;
    *(uint4*)&Bs[sr][sk] = bv0;
    *(uint4*)&Bs[sr + 64][sk] = bv1;
    __syncthreads();
    bf16x8 af[4], bfv[4];
#pragma unroll
    for (int fr = 0; fr < 4; ++fr)
      af[fr] = *(const bf16x8*)&As[(wr << 6) + (fr << 4) + l15][slot << 3];
#pragma unroll
    for (int fc = 0; fc < 4; ++fc)
      bfv[fc] = *(const bf16x8*)&Bs[(wc << 6) + (fc << 4) + l15][slot << 3];
#pragma unroll
    for (int fr = 0; fr < 4; ++fr)
#pragma unroll
      for (int fc = 0; fc < 4; ++fc)
        acc[fr][fc] = __builtin_amdgcn_mfma_f32_16x16x32_bf16(af[fr], bfv[fc], acc[fr][fc], 0, 0, 0);
  }

  // Epilogue. C/D layout (m89-verified): col = lane&15, row = (lane>>4)*4 + reg.
#pragma unroll
  for (int fr = 0; fr < 4; ++fr) {
#pragma unroll
    for (int j = 0; j < 4; ++j) {
      const int grow = row0 + (wr << 6) + (fr << 4) + (slot << 2) + j;
      float rs = 0.f;
#pragma unroll
      for (int fc = 0; fc < 4; ++fc) {
        const int gcol = col0 + (wc << 6) + (fc << 4) + l15;
        const float v = acc[fr][fc][j];
        const size_t idx = cb + (size_t)grow * NN_ + gcol;
        if constexpr (MODE == 0) {
          C[idx] = f2b(v);
        } else if constexpr (MODE == 1) {
          C[idx] = f2b(v);
          if (grow != gcol) rs += expf(v * INV_T);
        } else if constexpr (MODE == 2) {
          rs += expf(v * INV_T);
        } else {  // MODE 3
          C[idx] = f2b(v + b2f(add1[idx]) + b2f(add2[idx]));
        }
      }
      if constexpr (MODE == 1 || MODE == 2) {
#pragma unroll
        for (int o = 1; o < 16; o <<= 1) rs += __shfl_xor(rs, o);
        if (l15 == 0) atomicAdd(&den[(size_t)b * NN_ + grow], rs);
      }
    }
  }
}

// ---------------- in-place row softmax on bf16 matrix ----------------
__global__ __launch_bounds__(256) void k_softmax(ushort* __restrict__ S) {
  const size_t row = blockIdx.x;
  const int t = threadIdx.x;
  ushort* sr = S + row * (size_t)NN_;
  ushort4 u = *(const ushort4*)&sr[t << 2];
  float v0 = b2f(u.x), v1 = b2f(u.y), v2 = b2f(u.z), v3 = b2f(u.w);
  float m = fmaxf(fmaxf(v0, v1), fmaxf(v2, v3));
#pragma unroll
  for (int o = 32; o; o >>= 1) m = fmaxf(m, __shfl_xor(m, o));
  __shared__ float pm[4], ps[4];
  if ((t & 63) == 0) pm[t >> 6] = m;
  __syncthreads();
  m = fmaxf(fmaxf(pm[0], pm[1]), fmaxf(pm[2], pm[3]));
  const float e0 = expf(v0 - m), e1 = expf(v1 - m), e2 = expf(v2 - m), e3 = expf(v3 - m);
  float s = e0 + e1 + e2 + e3;
#pragma unroll
  for (int o = 32; o; o >>= 1) s += __shfl_xor(s, o);
  if ((t & 63) == 0) ps[t >> 6] = s;
  __syncthreads();
  s = ps[0] + ps[1] + ps[2] + ps[3];
  const float inv = 1.0f / s;
  ushort4 w;
  w.x = f2b(e0 * inv); w.y = f2b(e1 * inv); w.z = f2b(e2 * inv); w.w = f2b(e3 * inv);
  *(ushort4*)&sr[t << 2] = w;
}

// ---------------- bf16 NxN transpose (per batch), 64x64 tiles ----------------
__global__ __launch_bounds__(256) void k_transpose(const ushort* __restrict__ in, ushort* __restrict__ out) {
  const int b = blockIdx.z;
  const size_t mb = (size_t)b * NN_ * NN_;
  const int bx = blockIdx.x, by = blockIdx.y;
  __shared__ ushort tl[64][65];
  const int t = threadIdx.x;
  const int r = t >> 3, c = (t & 7) << 3;  // r 0..31, c 0..56
#pragma unroll
  for (int h = 0; h < 2; ++h) {
    const int rr = r + h * 32;
    uint4 v = *(const uint4*)&in[mb + (size_t)(by * 64 + rr) * NN_ + bx * 64 + c];
    const ushort* pv = (const ushort*)&v;
#pragma unroll
    for (int e = 0; e < 8; ++e) tl[rr][c + e] = pv[e];
  }
  __syncthreads();
#pragma unroll
  for (int h = 0; h < 2; ++h) {
    const int rr = r + h * 32;
    ushort tmp[8];
#pragma unroll
    for (int e = 0; e < 8; ++e) tmp[e] = tl[c + e][rr];
    *(uint4*)&out[mb + (size_t)(bx * 64 + rr) * NN_ + by * 64 + c] = *(const uint4*)tmp;
  }
}

// ---------------- per-row top-5 + numerator + loss ----------------
__global__ __launch_bounds__(64) void k_topk(const ushort* __restrict__ Ssum, const ushort* __restrict__ znS,
                                             const ushort* __restrict__ znO, const float* __restrict__ den,
                                             float* __restrict__ lossRows, int halfOff) {
  const int gid = blockIdx.x;  // b*1024 + i
  const int b = gid >> 10, i = gid & 1023;
  const int lane = threadIdx.x;
  const size_t rowoff = (size_t)gid << 10;

  float sc[16];
#pragma unroll
  for (int tt = 0; tt < 16; ++tt) {
    const int j = tt * 64 + lane;
    const float a = b2f(Ssum[rowoff + j]);
    const float dd = (float)(j - i);
    const float pw = expf(-dd * dd * 0.125f);
    sc[tt] = 0.5f * pw + a * (0.5f / 3.0f);
  }

  float pv[5]; int pidx[5];
#pragma unroll
  for (int it = 0; it < 5; ++it) {
    float bv = -INFINITY; int bi = 0x7fffffff;
#pragma unroll
    for (int tt = 0; tt < 16; ++tt) {
      const int j = tt * 64 + lane;
      if (sc[tt] > bv || (sc[tt] == bv && j < bi)) { bv = sc[tt]; bi = j; }
    }
#pragma unroll
    for (int o = 32; o; o >>= 1) {
      const float ov = __shfl_xor(bv, o);
      const int oi = __shfl_xor(bi, o);
      if (ov > bv || (ov == bv && oi < bi)) { bv = ov; bi = oi; }
    }
    pv[it] = bv; pidx[it] = bi;
    if ((bi & 63) == lane) sc[bi >> 6] = -INFINITY;
  }

  const ushort4 qr = *(const ushort4*)&znS[((size_t)b * NN_ + i) * DD + (lane << 2)];
  const float q0 = b2f(qr.x), q1 = b2f(qr.y), q2 = b2f(qr.z), q3 = b2f(qr.w);

  auto rowdot = [&](int j) -> float {
    const ushort4 orr = *(const ushort4*)&znO[((size_t)b * NN_ + j) * DD + (lane << 2)];
    float p = q0 * b2f(orr.x) + q1 * b2f(orr.y) + q2 * b2f(orr.z) + q3 * b2f(orr.w);
#pragma unroll
    for (int o = 32; o; o >>= 1) p += __shfl_xor(p, o);
    return p;
  };

  float num = expf(rowdot(i) * INV_T);  // strong term
#pragma unroll
  for (int it = 0; it < 5; ++it)
    if (pidx[it] != i) num += pv[it] * expf(rowdot(pidx[it]) * INV_T);

  if (lane == 0) {
    const float dn = den[(size_t)b * NN_ + i];
    lossRows[(size_t)b * (2 * NN_) + halfOff + i] = -logf(num / (dn + 1e-9f) + 1e-9f);
  }
}

// ---------------- final mean ----------------
__global__ __launch_bounds__(256) void k_final(const float* __restrict__ lossRows, float* __restrict__ out) {
  const int t = threadIdx.x;
  float s = 0.f;
  for (int idx = t; idx < BB * 2 * NN_; idx += 256) s += lossRows[idx];
#pragma unroll
  for (int o = 32; o; o >>= 1) s += __shfl_xor(s, o);
  __shared__ float p[4];
  if ((t & 63) == 0) p[t >> 6] = s;
  __syncthreads();
  if (t == 0) out[0] = (p[0] + p[1] + p[2] + p[3]) / (float)(BB * 2 * NN_);
}

extern "C" void kernel_launch(void* const* d_in, const int* in_sizes, int n_in, void* d_out, int out_size,
                              void* d_ws, size_t ws_size, hipStream_t stream) {
  const float* z1 = (const float*)d_in[0];
  const float* z2 = (const float*)d_in[1];
  float* out = (float*)d_out;

  const size_t nzd = (size_t)BB * NN_ * DD;   // 4.19M
  const size_t nnn = (size_t)BB * NN_ * NN_;  // 16.78M

  ushort* zn1 = (ushort*)d_ws;
  ushort* zn2 = zn1 + nzd;
  ushort* X = zn2 + nzd;
  ushort* Y = X + nnn;
  ushort* Z = Y + nnn;
  float* den1 = (float*)(Z + nnn);
  float* den2 = den1 + (size_t)BB * NN_;
  float* lossRows = den2 + (size_t)BB * NN_;

  const size_t needed = 2 * nzd * 2 + 3 * nnn * 2 + 2 * (size_t)BB * NN_ * 4 + 2 * (size_t)BB * NN_ * 4;
  if (ws_size < needed) return;  // fail cleanly (absmax) instead of faulting

  dim3 blk(256);
  dim3 gG(NN_ / 128, NN_ / 128, BB);
  dim3 gT(NN_ / 64, NN_ / 64, BB);

  hipMemsetAsync(den1, 0, 2 * (size_t)BB * NN_ * 4, stream);

  k_norm<<<BB * NN_, blk, 0, stream>>>(z1, zn1);
  k_norm<<<BB * NN_, blk, 0, stream>>>(z2, zn2);

  // half 2 first: X = S22 (+den2 same-half part), softmax -> A2
  k_gemm_nt<1><<<gG, blk, 0, stream>>>(zn2, zn2, X, nullptr, nullptr, den2, DD);
  k_softmax<<<BB * NN_, blk, 0, stream>>>(X);
  k_transpose<<<gT, blk, 0, stream>>>(X, Y);                                     // Y = A2^T
  k_gemm_nt<0><<<gG, blk, 0, stream>>>(X, Y, Z, nullptr, nullptr, nullptr, NN_); // Z = A2^2
  k_transpose<<<gT, blk, 0, stream>>>(Z, Y);                                     // Y = (A2^2)^T
  k_gemm_nt<3><<<gG, blk, 0, stream>>>(Z, Y, X, X, Z, nullptr, NN_);             // X = A2+A2^2+A2^4 = sum2

  // cross den parts
  k_gemm_nt<2><<<gG, blk, 0, stream>>>(zn1, zn2, nullptr, nullptr, nullptr, den1, DD);
  k_gemm_nt<2><<<gG, blk, 0, stream>>>(zn2, zn1, nullptr, nullptr, nullptr, den2, DD);

  // half 1: Z = S11 (+den1 same-half part), softmax -> A1
  k_gemm_nt<1><<<gG, blk, 0, stream>>>(zn1, zn1, Z, nullptr, nullptr, den1, DD);
  k_softmax<<<BB * NN_, blk, 0, stream>>>(Z);

  // loss rows for half 1 (uses sum2, den1)
  k_topk<<<BB * NN_, dim3(64), 0, stream>>>(X, zn1, zn2, den1, lossRows, 0);

  k_transpose<<<gT, blk, 0, stream>>>(Z, Y);                                     // Y = A1^T
  k_gemm_nt<0><<<gG, blk, 0, stream>>>(Z, Y, X, nullptr, nullptr, nullptr, NN_); // X = A1^2
  k_transpose<<<gT, blk, 0, stream>>>(X, Y);                                     // Y = (A1^2)^T
  k_gemm_nt<3><<<gG, blk, 0, stream>>>(X, Y, Z, Z, X, nullptr, NN_);             // Z = sum1

  // loss rows for half 2 (uses sum1, den2)
  k_topk<<<BB * NN_, dim3(64), 0, stream>>>(Z, zn2, zn1, den2, lossRows, NN_);

  k_final<<<1, blk, 0, stream>>>(lossRows, out);
}

// Round 3
// 580.150 us; speedup vs baseline: 1.1157x; 1.1157x over previous
//
#include <hip/hip_runtime.h>
#include <cmath>
#include <cstdint>

#define BB 16
#define NN_ 1024
#define DD 256

constexpr float INV_T = 1.0f / 0.07f;

typedef __attribute__((ext_vector_type(8))) short bf16x8;
typedef __attribute__((ext_vector_type(4))) float f32x4;

static __device__ __forceinline__ float b2f(ushort u) {
  union { uint i; float f; } c; c.i = ((uint)u) << 16; return c.f;
}
static __device__ __forceinline__ ushort f2b(float f) {
  union { float f; uint i; } c; c.f = f;
  uint r = c.i + 0x7fffu + ((c.i >> 16) & 1u);
  return (ushort)(r >> 16);
}

// ---------------- row normalize: z(f32) -> zn(bf16), both halves in one launch ----------------
__global__ __launch_bounds__(256) void k_norm(const float* __restrict__ z1, const float* __restrict__ z2,
                                              ushort* __restrict__ znAll) {
  const int row = blockIdx.x;  // 0 .. 2*BB*NN_-1
  const int t = threadIdx.x;
  const bool second = row >= BB * NN_;
  const float* z = second ? z2 : z1;
  const size_t inBase = (size_t)(second ? row - BB * NN_ : row) * DD + t;
  float v = z[inBase];
  float ss = v * v;
#pragma unroll
  for (int o = 32; o; o >>= 1) ss += __shfl_xor(ss, o);
  __shared__ float par[4];
  if ((t & 63) == 0) par[t >> 6] = ss;
  __syncthreads();
  float tot = par[0] + par[1] + par[2] + par[3];
  znAll[(size_t)row * DD + t] = f2b(v / (sqrtf(tot) + 1e-12f));
}

// ---------------- MFMA NT GEMM: C = U * V^T, U:[N][K], V:[N][K] bf16 ----------------
// Flat 1024-block grid, XCD-batch-affinity decode: block i -> XCD i&7, each XCD owns 2
// batches processed one at a time so per-XCD L2 working set = one batch's A+B = 4 MB.
// MODE 0: store bf16 C
// MODE 1: store bf16 C + denR[row] += sum_col exp(c*INV_T) skipping row==col
// MODE 2: no store; denR[row] += row-sums of exp, denC[col] += col-sums of exp (S21=S12^T)
// MODE 3: store C = bf16( acc + add1[pos] + add2[pos] )
template <int MODE>
__global__ __launch_bounds__(256) void k_gemm_nt(const ushort* __restrict__ U, const ushort* __restrict__ V,
                                                 ushort* __restrict__ C, const ushort* __restrict__ add1,
                                                 const ushort* __restrict__ add2, float* __restrict__ denR,
                                                 float* __restrict__ denC, int K) {
  __shared__ __align__(16) short As[128][56];
  __shared__ __align__(16) short Bs[128][56];
  const int t = threadIdx.x;
  // --- XCD-affinity decode ---
  const int fid = blockIdx.x;
  const int xcd = fid & 7, j = fid >> 3;
  const int b = (xcd << 1) | (j >> 6);
  const int jj = j & 63;
  const int row0 = (jj >> 3) << 7, col0 = (jj & 7) << 7;

  const size_t ub = (size_t)b * NN_ * K;
  const size_t cb = (size_t)b * NN_ * NN_;
  const int lane = t & 63, wv = t >> 6;
  const int wr = wv >> 1, wc = wv & 1;
  const int l15 = lane & 15, slot = lane >> 4;
  const int sr = t >> 2;        // 0..63
  const int sk = (t & 3) << 3;  // 0,8,16,24

  f32x4 acc[4][4];
#pragma unroll
  for (int i = 0; i < 4; ++i)
#pragma unroll
    for (int jx = 0; jx < 4; ++jx)
#pragma unroll
      for (int e = 0; e < 4; ++e) acc[i][jx][e] = 0.f;

  for (int k0 = 0; k0 < K; k0 += 32) {
    const ushort* up = U + ub + (size_t)(row0 + sr) * K + (k0 + sk);
    const uint4 av0 = *(const uint4*)up;
    const uint4 av1 = *(const uint4*)(up + (size_t)64 * K);
    const ushort* vp = V + ub + (size_t)(col0 + sr) * K + (k0 + sk);
    const uint4 bv0 = *(const uint4*)vp;
    const uint4 bv1 = *(const uint4*)(vp + (size_t)64 * K);
    __syncthreads();  // previous iteration's fragment reads complete
    *(uint4*)&As[sr][sk] = av0;
    *(uint4*)&As[sr + 64][sk] = av1;
    *(uint4*)&Bs[sr][sk] = bv0;
    *(uint4*)&Bs[sr + 64][sk] = bv1;
    __syncthreads();
    bf16x8 af[4], bfv[4];
#pragma unroll
    for (int fr = 0; fr < 4; ++fr)
      af[fr] = *(const bf16x8*)&As[(wr << 6) + (fr << 4) + l15][slot << 3];
#pragma unroll
    for (int fc = 0; fc < 4; ++fc)
      bfv[fc] = *(const bf16x8*)&Bs[(wc << 6) + (fc << 4) + l15][slot << 3];
#pragma unroll
    for (int fr = 0; fr < 4; ++fr)
#pragma unroll
      for (int fc = 0; fc < 4; ++fc)
        acc[fr][fc] = __builtin_amdgcn_mfma_f32_16x16x32_bf16(af[fr], bfv[fc], acc[fr][fc], 0, 0, 0);
  }

  // Epilogue. C/D layout (m89-verified): col = lane&15, row = (lane>>4)*4 + reg.
  if constexpr (MODE == 2) {
    float colp[4] = {0.f, 0.f, 0.f, 0.f};
#pragma unroll
    for (int fr = 0; fr < 4; ++fr) {
#pragma unroll
      for (int jx = 0; jx < 4; ++jx) {
        const int grow = row0 + (wr << 6) + (fr << 4) + (slot << 2) + jx;
        float rs = 0.f;
#pragma unroll
        for (int fc = 0; fc < 4; ++fc) {
          const float e = expf(acc[fr][fc][jx] * INV_T);
          rs += e;
          colp[fc] += e;
        }
#pragma unroll
        for (int o = 1; o < 16; o <<= 1) rs += __shfl_xor(rs, o);
        if (l15 == 0) atomicAdd(&denR[(size_t)b * NN_ + grow], rs);
      }
    }
#pragma unroll
    for (int fc = 0; fc < 4; ++fc) {
      float cs = colp[fc];
      cs += __shfl_xor(cs, 16);
      cs += __shfl_xor(cs, 32);
      if (slot == 0) atomicAdd(&denC[(size_t)b * NN_ + col0 + (wc << 6) + (fc << 4) + l15], cs);
    }
  } else {
#pragma unroll
    for (int fr = 0; fr < 4; ++fr) {
#pragma unroll
      for (int jx = 0; jx < 4; ++jx) {
        const int grow = row0 + (wr << 6) + (fr << 4) + (slot << 2) + jx;
        float rs = 0.f;
#pragma unroll
        for (int fc = 0; fc < 4; ++fc) {
          const int gcol = col0 + (wc << 6) + (fc << 4) + l15;
          const float v = acc[fr][fc][jx];
          const size_t idx = cb + (size_t)grow * NN_ + gcol;
          if constexpr (MODE == 0) {
            C[idx] = f2b(v);
          } else if constexpr (MODE == 1) {
            C[idx] = f2b(v);
            if (grow != gcol) rs += expf(v * INV_T);
          } else {  // MODE 3
            C[idx] = f2b(v + b2f(add1[idx]) + b2f(add2[idx]));
          }
        }
        if constexpr (MODE == 1) {
#pragma unroll
          for (int o = 1; o < 16; o <<= 1) rs += __shfl_xor(rs, o);
          if (l15 == 0) atomicAdd(&denR[(size_t)b * NN_ + grow], rs);
        }
      }
    }
  }
}

// ---------------- in-place row softmax on bf16 matrix ----------------
__global__ __launch_bounds__(256) void k_softmax(ushort* __restrict__ S) {
  const size_t row = blockIdx.x;
  const int t = threadIdx.x;
  ushort* sr = S + row * (size_t)NN_;
  ushort4 u = *(const ushort4*)&sr[t << 2];
  float v0 = b2f(u.x), v1 = b2f(u.y), v2 = b2f(u.z), v3 = b2f(u.w);
  float m = fmaxf(fmaxf(v0, v1), fmaxf(v2, v3));
#pragma unroll
  for (int o = 32; o; o >>= 1) m = fmaxf(m, __shfl_xor(m, o));
  __shared__ float pm[4], ps[4];
  if ((t & 63) == 0) pm[t >> 6] = m;
  __syncthreads();
  m = fmaxf(fmaxf(pm[0], pm[1]), fmaxf(pm[2], pm[3]));
  const float e0 = expf(v0 - m), e1 = expf(v1 - m), e2 = expf(v2 - m), e3 = expf(v3 - m);
  float s = e0 + e1 + e2 + e3;
#pragma unroll
  for (int o = 32; o; o >>= 1) s += __shfl_xor(s, o);
  if ((t & 63) == 0) ps[t >> 6] = s;
  __syncthreads();
  s = ps[0] + ps[1] + ps[2] + ps[3];
  const float inv = 1.0f / s;
  ushort4 w;
  w.x = f2b(e0 * inv); w.y = f2b(e1 * inv); w.z = f2b(e2 * inv); w.w = f2b(e3 * inv);
  *(ushort4*)&sr[t << 2] = w;
}

// ---------------- bf16 NxN transpose (per batch), 64x64 tiles ----------------
__global__ __launch_bounds__(256) void k_transpose(const ushort* __restrict__ in, ushort* __restrict__ out) {
  const int b = blockIdx.z;
  const size_t mb = (size_t)b * NN_ * NN_;
  const int bx = blockIdx.x, by = blockIdx.y;
  __shared__ ushort tl[64][65];
  const int t = threadIdx.x;
  const int r = t >> 3, c = (t & 7) << 3;  // r 0..31, c 0..56
#pragma unroll
  for (int h = 0; h < 2; ++h) {
    const int rr = r + h * 32;
    uint4 v = *(const uint4*)&in[mb + (size_t)(by * 64 + rr) * NN_ + bx * 64 + c];
    const ushort* pv = (const ushort*)&v;
#pragma unroll
    for (int e = 0; e < 8; ++e) tl[rr][c + e] = pv[e];
  }
  __syncthreads();
#pragma unroll
  for (int h = 0; h < 2; ++h) {
    const int rr = r + h * 32;
    ushort tmp[8];
#pragma unroll
    for (int e = 0; e < 8; ++e) tmp[e] = tl[c + e][rr];
    *(uint4*)&out[mb + (size_t)(bx * 64 + rr) * NN_ + by * 64 + c] = *(const uint4*)tmp;
  }
}

// ---------------- per-row top-5 + numerator + loss ----------------
__global__ __launch_bounds__(64) void k_topk(const ushort* __restrict__ Ssum, const ushort* __restrict__ znS,
                                             const ushort* __restrict__ znO, const float* __restrict__ den,
                                             float* __restrict__ lossRows, int halfOff) {
  const int gid = blockIdx.x;  // b*1024 + i
  const int b = gid >> 10, i = gid & 1023;
  const int lane = threadIdx.x;
  const size_t rowoff = (size_t)gid << 10;

  float sc[16];
#pragma unroll
  for (int tt = 0; tt < 16; ++tt) {
    const int j = tt * 64 + lane;
    const float a = b2f(Ssum[rowoff + j]);
    const float dd = (float)(j - i);
    const float pw = expf(-dd * dd * 0.125f);
    sc[tt] = 0.5f * pw + a * (0.5f / 3.0f);
  }

  float pv[5]; int pidx[5];
#pragma unroll
  for (int it = 0; it < 5; ++it) {
    float bv = -INFINITY; int bi = 0x7fffffff;
#pragma unroll
    for (int tt = 0; tt < 16; ++tt) {
      const int j = tt * 64 + lane;
      if (sc[tt] > bv || (sc[tt] == bv && j < bi)) { bv = sc[tt]; bi = j; }
    }
#pragma unroll
    for (int o = 32; o; o >>= 1) {
      const float ov = __shfl_xor(bv, o);
      const int oi = __shfl_xor(bi, o);
      if (ov > bv || (ov == bv && oi < bi)) { bv = ov; bi = oi; }
    }
    pv[it] = bv; pidx[it] = bi;
    if ((bi & 63) == lane) sc[bi >> 6] = -INFINITY;
  }

  const ushort4 qr = *(const ushort4*)&znS[((size_t)b * NN_ + i) * DD + (lane << 2)];
  const float q0 = b2f(qr.x), q1 = b2f(qr.y), q2 = b2f(qr.z), q3 = b2f(qr.w);

  auto rowdot = [&](int j) -> float {
    const ushort4 orr = *(const ushort4*)&znO[((size_t)b * NN_ + j) * DD + (lane << 2)];
    float p = q0 * b2f(orr.x) + q1 * b2f(orr.y) + q2 * b2f(orr.z) + q3 * b2f(orr.w);
#pragma unroll
    for (int o = 32; o; o >>= 1) p += __shfl_xor(p, o);
    return p;
  };

  float num = expf(rowdot(i) * INV_T);  // strong term
#pragma unroll
  for (int it = 0; it < 5; ++it)
    if (pidx[it] != i) num += pv[it] * expf(rowdot(pidx[it]) * INV_T);

  if (lane == 0) {
    const float dn = den[(size_t)b * NN_ + i];
    lossRows[(size_t)b * (2 * NN_) + halfOff + i] = -logf(num / (dn + 1e-9f) + 1e-9f);
  }
}

// ---------------- final mean ----------------
__global__ __launch_bounds__(256) void k_final(const float* __restrict__ lossRows, float* __restrict__ out) {
  const int t = threadIdx.x;
  float s = 0.f;
  for (int idx = t; idx < BB * 2 * NN_; idx += 256) s += lossRows[idx];
#pragma unroll
  for (int o = 32; o; o >>= 1) s += __shfl_xor(s, o);
  __shared__ float p[4];
  if ((t & 63) == 0) p[t >> 6] = s;
  __syncthreads();
  if (t == 0) out[0] = (p[0] + p[1] + p[2] + p[3]) / (float)(BB * 2 * NN_);
}

extern "C" void kernel_launch(void* const* d_in, const int* in_sizes, int n_in, void* d_out, int out_size,
                              void* d_ws, size_t ws_size, hipStream_t stream) {
  const float* z1 = (const float*)d_in[0];
  const float* z2 = (const float*)d_in[1];
  float* out = (float*)d_out;

  const size_t nzd = (size_t)BB * NN_ * DD;   // 4.19M
  const size_t nnn = (size_t)BB * NN_ * NN_;  // 16.78M

  ushort* zn1 = (ushort*)d_ws;
  ushort* zn2 = zn1 + nzd;
  ushort* X = zn2 + nzd;
  ushort* Y = X + nnn;
  ushort* Z = Y + nnn;
  float* den1 = (float*)(Z + nnn);
  float* den2 = den1 + (size_t)BB * NN_;
  float* lossRows = den2 + (size_t)BB * NN_;

  const size_t needed = 2 * nzd * 2 + 3 * nnn * 2 + 2 * (size_t)BB * NN_ * 4 + 2 * (size_t)BB * NN_ * 4;
  if (ws_size < needed) return;  // fail cleanly (absmax) instead of faulting

  dim3 blk(256);
  const int gFlat = (NN_ / 128) * (NN_ / 128) * BB;  // 1024
  dim3 gT(NN_ / 64, NN_ / 64, BB);

  hipMemsetAsync(den1, 0, 2 * (size_t)BB * NN_ * 4, stream);

  k_norm<<<2 * BB * NN_, blk, 0, stream>>>(z1, z2, zn1);

  // half 2 first: X = S22 (+den2 same-half part), softmax -> A2
  k_gemm_nt<1><<<gFlat, blk, 0, stream>>>(zn2, zn2, X, nullptr, nullptr, den2, nullptr, DD);
  k_softmax<<<BB * NN_, blk, 0, stream>>>(X);
  k_transpose<<<gT, blk, 0, stream>>>(X, Y);                                              // Y = A2^T
  k_gemm_nt<0><<<gFlat, blk, 0, stream>>>(X, Y, Z, nullptr, nullptr, nullptr, nullptr, NN_);  // Z = A2^2
  k_transpose<<<gT, blk, 0, stream>>>(Z, Y);                                              // Y = (A2^2)^T
  k_gemm_nt<3><<<gFlat, blk, 0, stream>>>(Z, Y, X, X, Z, nullptr, nullptr, NN_);          // X = A2+A2^2+A2^4

  // cross den contributions: one GEMM gives den1 rows AND den2 cols (S21 = S12^T)
  k_gemm_nt<2><<<gFlat, blk, 0, stream>>>(zn1, zn2, nullptr, nullptr, nullptr, den1, den2, DD);

  // half 1: Z = S11 (+den1 same-half part), softmax -> A1
  k_gemm_nt<1><<<gFlat, blk, 0, stream>>>(zn1, zn1, Z, nullptr, nullptr, den1, nullptr, DD);
  k_softmax<<<BB * NN_, blk, 0, stream>>>(Z);

  // loss rows for half 1 (uses sum2, den1)
  k_topk<<<BB * NN_, dim3(64), 0, stream>>>(X, zn1, zn2, den1, lossRows, 0);

  k_transpose<<<gT, blk, 0, stream>>>(Z, Y);                                              // Y = A1^T
  k_gemm_nt<0><<<gFlat, blk, 0, stream>>>(Z, Y, X, nullptr, nullptr, nullptr, nullptr, NN_);  // X = A1^2
  k_transpose<<<gT, blk, 0, stream>>>(X, Y);                                              // Y = (A1^2)^T
  k_gemm_nt<3><<<gFlat, blk, 0, stream>>>(X, Y, Z, Z, X, nullptr, nullptr, NN_);          // Z = sum1

  // loss rows for half 2 (uses sum1, den2)
  k_topk<<<BB * NN_, dim3(64), 0, stream>>>(Z, zn2, zn1, den2, lossRows, NN_);

  k_final<<<1, blk, 0, stream>>>(lossRows, out);
}